// Round 2
// baseline (3302.062 us; speedup 1.0000x reference)
//
#include <hip/hip_runtime.h>
#include <cstdio>

#define HH 2048
#define WW 2048
#define RAD 16
#define TILE 32
#define REGD 64          // TILE + 2*RAD
#define EPSF 1e-4f

constexpr size_t PLN = (size_t)HH * WW;

__device__ __forceinline__ int cnt1d(int p, int n) {
    int lo = p - RAD; if (lo < 0) lo = 0;
    int hi = p + RAD; if (hi > n - 1) hi = n - 1;
    return hi - lo + 1;
}

__device__ __forceinline__ void store4v(float* p, float a, float b, float c, float d) {
    *reinterpret_cast<float4*>(p) = make_float4(a, b, c, d);
}
__device__ __forceinline__ void store4v(_Float16* p, float a, float b, float c, float d) {
    union { _Float16 h[4]; uint2 u; } t;
    t.h[0] = (_Float16)a; t.h[1] = (_Float16)b; t.h[2] = (_Float16)c; t.h[3] = (_Float16)d;
    *reinterpret_cast<uint2*>(p) = t.u;
}

// Load a 64x64 region (tile +/- RAD) of one fp32 plane into LDS, zero-filled OOB.
__device__ __forceinline__ void load_region(float (&dst)[REGD][REGD],
                                            const float* __restrict__ plane,
                                            int y0, int x0, int tx) {
    for (int idx = tx; idx < REGD * REGD; idx += 256) {
        const int ry = idx >> 6, rx = idx & 63;
        const int gy = y0 - RAD + ry, gx = x0 - RAD + rx;
        float v = 0.f;
        if ((unsigned)gy < (unsigned)HH && (unsigned)gx < (unsigned)WW)
            v = plane[(size_t)gy * WW + gx];
        dst[ry][rx] = v;
    }
}

// One channel: vertical sliding column-sum (64 threads, stride-64 reads -> 2-way banks, free),
// then horizontal box accumulate into S[CH][0..3] (cs padded [32][65] -> ~2-way, free).
template<int CH, int SA, int SB, int NCH>
__device__ __forceinline__ void proc_ch(float (&reg)[3][REGD][REGD],
                                        float (&cs)[TILE][REGD + 1],
                                        float (&S)[NCH][4],
                                        int tx, int prow, int pcol) {
    if (tx < REGD) {
        const int col = tx;
        float acc = 0.f;
        for (int t = 0; t <= 2 * RAD; ++t) {
            float v = reg[SA][t][col];
            if constexpr (SB >= 0) v *= reg[SB][t][col];
            acc += v;
        }
        cs[0][col] = acc;
        for (int r = 1; r < TILE; ++r) {
            float va = reg[SA][r + 2 * RAD][col];
            float vb = reg[SA][r - 1][col];
            if constexpr (SB >= 0) {
                va *= reg[SB][r + 2 * RAD][col];
                vb *= reg[SB][r - 1][col];
            }
            acc += va - vb;
            cs[r][col] = acc;
        }
    }
    __syncthreads();
    float h = 0.f;
    for (int x = 0; x <= 2 * RAD; ++x) h += cs[prow][pcol + x];
    S[CH][0] = h;
#pragma unroll
    for (int k = 1; k < 4; ++k) {
        h += cs[prow][pcol + 2 * RAD + k] - cs[prow][pcol + k - 1];
        S[CH][k] = h;
    }
    __syncthreads();
}

// Stage 1: fused 2D box sums of 21 product channels + per-pixel 3x3 solve -> a,b (12 planes).
template<typename TS>
__global__ __launch_bounds__(256, 2) void k_ab(const float* __restrict__ g,
                                               const float* __restrict__ s,
                                               TS* __restrict__ ab) {
    __shared__ float reg[3][REGD][REGD];
    __shared__ float cs[TILE][REGD + 1];
    const int tx = threadIdx.x;
    const int x0 = blockIdx.x * TILE, y0 = blockIdx.y * TILE;
    const int prow = tx >> 3;
    const int pcol = (tx & 7) * 4;
    float S[21][4];

    const float* g0 = g;
    const float* g1 = g + PLN;
    const float* g2 = g + 2 * PLN;
    const float* s0 = s;
    const float* s1 = s + PLN;
    const float* s2 = s + 2 * PLN;

    // Phase A: slots = [g0, g1, g2]
    load_region(reg[0], g0, y0, x0, tx);
    load_region(reg[1], g1, y0, x0, tx);
    load_region(reg[2], g2, y0, x0, tx);
    __syncthreads();
    proc_ch<0, 0, -1>(reg, cs, S, tx, prow, pcol);   // g0
    proc_ch<1, 1, -1>(reg, cs, S, tx, prow, pcol);   // g1
    proc_ch<2, 2, -1>(reg, cs, S, tx, prow, pcol);   // g2
    proc_ch<15, 0, 0>(reg, cs, S, tx, prow, pcol);   // g0*g0
    proc_ch<16, 0, 1>(reg, cs, S, tx, prow, pcol);   // g0*g1
    proc_ch<17, 0, 2>(reg, cs, S, tx, prow, pcol);   // g0*g2
    proc_ch<18, 1, 1>(reg, cs, S, tx, prow, pcol);   // g1*g1
    proc_ch<19, 1, 2>(reg, cs, S, tx, prow, pcol);   // g1*g2
    proc_ch<20, 2, 2>(reg, cs, S, tx, prow, pcol);   // g2*g2
    // Phase B: slot2 <- s0  => [g0, g1, s0]
    load_region(reg[2], s0, y0, x0, tx);
    __syncthreads();
    proc_ch<3, 2, -1>(reg, cs, S, tx, prow, pcol);   // s0
    proc_ch<6, 0, 2>(reg, cs, S, tx, prow, pcol);    // g0*s0
    proc_ch<9, 1, 2>(reg, cs, S, tx, prow, pcol);    // g1*s0
    // Phase C: slot2 <- s1
    load_region(reg[2], s1, y0, x0, tx);
    __syncthreads();
    proc_ch<4, 2, -1>(reg, cs, S, tx, prow, pcol);   // s1
    proc_ch<7, 0, 2>(reg, cs, S, tx, prow, pcol);    // g0*s1
    proc_ch<10, 1, 2>(reg, cs, S, tx, prow, pcol);   // g1*s1
    // Phase D: slot2 <- s2
    load_region(reg[2], s2, y0, x0, tx);
    __syncthreads();
    proc_ch<5, 2, -1>(reg, cs, S, tx, prow, pcol);   // s2
    proc_ch<8, 0, 2>(reg, cs, S, tx, prow, pcol);    // g0*s2
    proc_ch<11, 1, 2>(reg, cs, S, tx, prow, pcol);   // g1*s2
    // Phase E: slot0 <- g2, slot1 <- s0  => [g2, s0, s2]
    load_region(reg[0], g2, y0, x0, tx);
    load_region(reg[1], s0, y0, x0, tx);
    __syncthreads();
    proc_ch<12, 0, 1>(reg, cs, S, tx, prow, pcol);   // g2*s0
    proc_ch<14, 0, 2>(reg, cs, S, tx, prow, pcol);   // g2*s2
    // Phase F: slot1 <- s1
    load_region(reg[1], s1, y0, x0, tx);
    __syncthreads();
    proc_ch<13, 0, 1>(reg, cs, S, tx, prow, pcol);   // g2*s1

    // Per-pixel covariance, 3x3 inverse, a, b.
    const int Y = y0 + prow;
    const int cntY = cnt1d(Y, HH);
    float o[12][4];
#pragma unroll
    for (int k = 0; k < 4; ++k) {
        const int X = x0 + pcol + k;
        const float rN = 1.0f / (float)(cntY * cnt1d(X, WW));
        const float m0 = S[0][k] * rN, m1 = S[1][k] * rN, m2 = S[2][k] * rN;
        const float p0 = S[3][k] * rN, p1 = S[4][k] * rN, p2 = S[5][k] * rN;
        const float c00 = S[6][k]  * rN - m0 * p0;
        const float c01 = S[7][k]  * rN - m0 * p1;
        const float c02 = S[8][k]  * rN - m0 * p2;
        const float c10 = S[9][k]  * rN - m1 * p0;
        const float c11 = S[10][k] * rN - m1 * p1;
        const float c12 = S[11][k] * rN - m1 * p2;
        const float c20 = S[12][k] * rN - m2 * p0;
        const float c21 = S[13][k] * rN - m2 * p1;
        const float c22 = S[14][k] * rN - m2 * p2;
        const float vrr = S[15][k] * rN - m0 * m0 + EPSF;
        const float vrg = S[16][k] * rN - m0 * m1;
        const float vrb = S[17][k] * rN - m0 * m2;
        const float vgg = S[18][k] * rN - m1 * m1 + EPSF;
        const float vgb = S[19][k] * rN - m1 * m2;
        const float vbb = S[20][k] * rN - m2 * m2 + EPSF;
        const float det = vrr * vgg * vbb + vrg * vgb * vrb + vrb * vrg * vgb
                        - vrb * vgg * vrb - vrg * vrg * vbb - vrr * vgb * vgb;
        const float id = 1.0f / det;
        const float irr =  (vgg * vbb - vgb * vgb) * id;
        const float irg = -(vrg * vbb - vrb * vgb) * id;
        const float irb =  (vrg * vgb - vrb * vgg) * id;
        const float igg =  (vrr * vbb - vrb * vrb) * id;
        const float igb = -(vrr * vgb - vrb * vrg) * id;
        const float ibb =  (vrr * vgg - vrg * vrg) * id;
        const float a00 = c00 * irr + c10 * irg + c20 * irb;
        const float a01 = c01 * irr + c11 * irg + c21 * irb;
        const float a02 = c02 * irr + c12 * irg + c22 * irb;
        const float a10 = c00 * irg + c10 * igg + c20 * igb;
        const float a11 = c01 * irg + c11 * igg + c21 * igb;
        const float a12 = c02 * irg + c12 * igg + c22 * igb;
        const float a20 = c00 * irb + c10 * igb + c20 * ibb;
        const float a21 = c01 * irb + c11 * igb + c21 * ibb;
        const float a22 = c02 * irb + c12 * igb + c22 * ibb;
        o[0][k] = a00; o[1][k] = a01; o[2][k] = a02;
        o[3][k] = a10; o[4][k] = a11; o[5][k] = a12;
        o[6][k] = a20; o[7][k] = a21; o[8][k] = a22;
        o[9][k]  = p0 - a00 * m0 - a10 * m1 - a20 * m2;
        o[10][k] = p1 - a01 * m0 - a11 * m1 - a21 * m2;
        o[11][k] = p2 - a02 * m0 - a12 * m1 - a22 * m2;
    }
    TS* base = ab + (size_t)Y * WW + (size_t)(x0 + pcol);
#pragma unroll
    for (int p = 0; p < 12; ++p)
        store4v(base + (size_t)p * PLN, o[p][0], o[p][1], o[p][2], o[p][3]);
}

// Stage 2: fused 2D box sums of a,b (12 planes) + q = mean_a . guide + mean_b.
template<typename TS>
__global__ __launch_bounds__(256) void k_q(const TS* __restrict__ ab,
                                           const float* __restrict__ g,
                                           float* __restrict__ outp) {
    __shared__ float reg[REGD][REGD];
    __shared__ float cs[TILE][REGD + 1];
    const int tx = threadIdx.x;
    const int x0 = blockIdx.x * TILE, y0 = blockIdx.y * TILE;
    const int prow = tx >> 3;
    const int pcol = (tx & 7) * 4;
    float S[12][4];

#pragma unroll
    for (int c = 0; c < 12; ++c) {
        for (int idx = tx; idx < REGD * REGD; idx += 256) {
            const int ry = idx >> 6, rx = idx & 63;
            const int gy = y0 - RAD + ry, gx = x0 - RAD + rx;
            float v = 0.f;
            if ((unsigned)gy < (unsigned)HH && (unsigned)gx < (unsigned)WW)
                v = (float)ab[(size_t)c * PLN + (size_t)gy * WW + gx];
            reg[ry][rx] = v;
        }
        __syncthreads();
        if (tx < REGD) {
            const int col = tx;
            float acc = 0.f;
            for (int t = 0; t <= 2 * RAD; ++t) acc += reg[t][col];
            cs[0][col] = acc;
            for (int r = 1; r < TILE; ++r) {
                acc += reg[r + 2 * RAD][col] - reg[r - 1][col];
                cs[r][col] = acc;
            }
        }
        __syncthreads();
        float h = 0.f;
        for (int x = 0; x <= 2 * RAD; ++x) h += cs[prow][pcol + x];
        S[c][0] = h;
#pragma unroll
        for (int k = 1; k < 4; ++k) {
            h += cs[prow][pcol + 2 * RAD + k] - cs[prow][pcol + k - 1];
            S[c][k] = h;
        }
        __syncthreads();
    }

    const int Y = y0 + prow;
    const int cntY = cnt1d(Y, HH);
    const size_t rowbase = (size_t)Y * WW + (size_t)(x0 + pcol);
    const float4 gv0 = *reinterpret_cast<const float4*>(g + rowbase);
    const float4 gv1 = *reinterpret_cast<const float4*>(g + PLN + rowbase);
    const float4 gv2 = *reinterpret_cast<const float4*>(g + 2 * PLN + rowbase);
    const float ga0[4] = {gv0.x, gv0.y, gv0.z, gv0.w};
    const float ga1[4] = {gv1.x, gv1.y, gv1.z, gv1.w};
    const float ga2[4] = {gv2.x, gv2.y, gv2.z, gv2.w};
    float q[3][4];
#pragma unroll
    for (int k = 0; k < 4; ++k) {
        const int X = x0 + pcol + k;
        const float rN = 1.0f / (float)(cntY * cnt1d(X, WW));
        q[0][k] = (S[0][k] * ga0[k] + S[3][k] * ga1[k] + S[6][k] * ga2[k] + S[9][k])  * rN;
        q[1][k] = (S[1][k] * ga0[k] + S[4][k] * ga1[k] + S[7][k] * ga2[k] + S[10][k]) * rN;
        q[2][k] = (S[2][k] * ga0[k] + S[5][k] * ga1[k] + S[8][k] * ga2[k] + S[11][k]) * rN;
    }
#pragma unroll
    for (int c = 0; c < 3; ++c)
        store4v(outp + (size_t)c * PLN + rowbase, q[c][0], q[c][1], q[c][2], q[c][3]);
}

extern "C" void kernel_launch(void* const* d_in, const int* in_sizes, int n_in,
                              void* d_out, int out_size, void* d_ws, size_t ws_size,
                              hipStream_t stream) {
    const float* g = (const float*)d_in[0];
    const float* s = (const float*)d_in[1];
    float* outp = (float*)d_out;

    fprintf(stderr, "[guidedfilter] ws_size=%zu out_size=%d\n", ws_size, out_size);

    dim3 blk(256, 1, 1);
    dim3 grd(WW / TILE, HH / TILE, 1);

    const size_t need_f32 = 12 * PLN * sizeof(float);    // 192 MiB
    if (ws_size >= need_f32) {
        float* ab = (float*)d_ws;
        k_ab<float><<<grd, blk, 0, stream>>>(g, s, ab);
        k_q<float><<<grd, blk, 0, stream>>>(ab, g, outp);
    } else {
        if (ws_size < 12 * PLN * sizeof(_Float16))
            fprintf(stderr, "[guidedfilter] WARNING: ws_size too small even for fp16 path!\n");
        _Float16* ab = (_Float16*)d_ws;
        k_ab<_Float16><<<grd, blk, 0, stream>>>(g, s, ab);
        k_q<_Float16><<<grd, blk, 0, stream>>>(ab, g, outp);
    }
}

// Round 3
// 1794.404 us; speedup vs baseline: 1.8402x; 1.8402x over previous
//
#include <hip/hip_runtime.h>
#include <cstdio>

#define HH 2048
#define WWI 2048
#define RAD 16
#define EPSF 1e-4f
#define SEGV 32
#define SEGH 16

typedef _Float16 h16;
constexpr size_t PLN = (size_t)HH * WWI;

__device__ __forceinline__ int cnt1d(int p) {
    int lo = p - RAD; if (lo < 0) lo = 0;
    int hi = p + RAD; if (hi > HH - 1) hi = HH - 1;
    return hi - lo + 1;
}

__device__ __forceinline__ void st2(h16* p, float a, float b) {
    union { h16 h[2]; unsigned u; } t;
    t.h[0] = (h16)a; t.h[1] = (h16)b;
    *reinterpret_cast<unsigned*>(p) = t.u;
}

// ---------------- K0: transpose guide strip -> gT (B-layout, fp16) ----------------
template<int SW>
__global__ __launch_bounds__(256) void k0_gt(const float* __restrict__ g,
                                             h16* __restrict__ gT, int cs0) {
    __shared__ float tile[64][65];
    const int tx = threadIdx.x;
    const int x0 = cs0 + blockIdx.x * 64;
    const int y0 = blockIdx.y * 64;
    const int c0 = tx & 63, r4 = tx >> 6;
    for (int c = 0; c < 3; ++c) {
#pragma unroll
        for (int k = 0; k < 16; ++k) {
            const int r = k * 4 + r4;
            tile[r][c0] = g[(size_t)c * PLN + (size_t)(y0 + r) * WWI + (x0 + c0)];
        }
        __syncthreads();
#pragma unroll
        for (int k = 0; k < 16; ++k) {
            const int r = k * 4 + r4;
            gT[((size_t)c * SW + (x0 - cs0 + r)) * HH + (y0 + c0)] = (h16)tile[c0][r];
        }
        __syncthreads();
    }
}

// ---------------- K1: products + vertical sliding box-sum -> vs21 (B-layout fp16) ----------------
template<bool ADD>
__device__ __forceinline__ void accum6(const float* __restrict__ g, const float* __restrict__ s,
                                       int row, int j, float S[21]) {
    const size_t b = (size_t)row * WWI + j;
    const float v0 = g[b], v1 = g[PLN + b], v2 = g[2 * PLN + b];
    const float v3 = s[b], v4 = s[PLN + b], v5 = s[2 * PLN + b];
    float p[21];
    p[0] = v0; p[1] = v1; p[2] = v2; p[3] = v3; p[4] = v4; p[5] = v5;
    p[6] = v0 * v3; p[7] = v0 * v4; p[8] = v0 * v5;
    p[9] = v1 * v3; p[10] = v1 * v4; p[11] = v1 * v5;
    p[12] = v2 * v3; p[13] = v2 * v4; p[14] = v2 * v5;
    p[15] = v0 * v0; p[16] = v0 * v1; p[17] = v0 * v2;
    p[18] = v1 * v1; p[19] = v1 * v2; p[20] = v2 * v2;
#pragma unroll
    for (int c = 0; c < 21; ++c) { if (ADD) S[c] += p[c]; else S[c] -= p[c]; }
}

template<int SW>
__global__ __launch_bounds__(256, 4) void k1v(const float* __restrict__ g, const float* __restrict__ s,
                                              h16* __restrict__ vs, int cs0, int lo1, int hi1) {
    constexpr int SWV = SW + 64;
    const int j = lo1 + blockIdx.x * 256 + threadIdx.x;
    if (j >= hi1) return;
    const int jl = j - (cs0 - 32);
    const int i0 = blockIdx.y * SEGV;
    float S[21];
#pragma unroll
    for (int c = 0; c < 21; ++c) S[c] = 0.0f;
    {
        int lo = i0 - RAD; if (lo < 0) lo = 0;
        int hi = i0 + RAD; if (hi > HH - 1) hi = HH - 1;
        for (int k = lo; k <= hi; ++k) accum6<true>(g, s, k, j, S);
    }
    h16* vb = vs + (size_t)jl * HH + i0;
    for (int ii = 0; ii < SEGV; ii += 2) {
        const int i = i0 + ii;
        float P[21];
#pragma unroll
        for (int c = 0; c < 21; ++c) P[c] = S[c];
        // advance window i -> i+1
        if (i + RAD + 1 < HH) accum6<true>(g, s, i + RAD + 1, j, S);
        if (i - RAD >= 0)     accum6<false>(g, s, i - RAD, j, S);
#pragma unroll
        for (int c = 0; c < 21; ++c)
            st2(vb + (size_t)c * SWV * HH + ii, P[c], S[c]);
        // advance window i+1 -> i+2
        if (i + RAD + 2 < HH) accum6<true>(g, s, i + RAD + 2, j, S);
        if (i + 1 - RAD >= 0) accum6<false>(g, s, i + 1 - RAD, j, S);
    }
}

// ---------------- per-pixel 3x3 solve ----------------
__device__ __forceinline__ void solve_ab(const float S[21], float rN, float o[12]) {
    const float m0 = S[0] * rN, m1 = S[1] * rN, m2 = S[2] * rN;
    const float p0 = S[3] * rN, p1 = S[4] * rN, p2 = S[5] * rN;
    const float c00 = S[6] * rN - m0 * p0;
    const float c01 = S[7] * rN - m0 * p1;
    const float c02 = S[8] * rN - m0 * p2;
    const float c10 = S[9] * rN - m1 * p0;
    const float c11 = S[10] * rN - m1 * p1;
    const float c12 = S[11] * rN - m1 * p2;
    const float c20 = S[12] * rN - m2 * p0;
    const float c21 = S[13] * rN - m2 * p1;
    const float c22 = S[14] * rN - m2 * p2;
    const float vrr = S[15] * rN - m0 * m0 + EPSF;
    const float vrg = S[16] * rN - m0 * m1;
    const float vrb = S[17] * rN - m0 * m2;
    const float vgg = S[18] * rN - m1 * m1 + EPSF;
    const float vgb = S[19] * rN - m1 * m2;
    const float vbb = S[20] * rN - m2 * m2 + EPSF;
    const float det = vrr * vgg * vbb + vrg * vgb * vrb + vrb * vrg * vgb
                    - vrb * vgg * vrb - vrg * vrg * vbb - vrr * vgb * vgb;
    const float id = 1.0f / det;
    const float irr =  (vgg * vbb - vgb * vgb) * id;
    const float irg = -(vrg * vbb - vrb * vgb) * id;
    const float irb =  (vrg * vgb - vrb * vgg) * id;
    const float igg =  (vrr * vbb - vrb * vrb) * id;
    const float igb = -(vrr * vgb - vrb * vrg) * id;
    const float ibb =  (vrr * vgg - vrg * vrg) * id;
    const float a00 = c00 * irr + c10 * irg + c20 * irb;
    const float a01 = c01 * irr + c11 * irg + c21 * irb;
    const float a02 = c02 * irr + c12 * irg + c22 * irb;
    const float a10 = c00 * irg + c10 * igg + c20 * igb;
    const float a11 = c01 * irg + c11 * igg + c21 * igb;
    const float a12 = c02 * irg + c12 * igg + c22 * igb;
    const float a20 = c00 * irb + c10 * igb + c20 * ibb;
    const float a21 = c01 * irb + c11 * igb + c21 * ibb;
    const float a22 = c02 * irb + c12 * igb + c22 * ibb;
    o[0] = a00; o[1] = a01; o[2] = a02;
    o[3] = a10; o[4] = a11; o[5] = a12;
    o[6] = a20; o[7] = a21; o[8] = a22;
    o[9]  = p0 - a00 * m0 - a10 * m1 - a20 * m2;
    o[10] = p1 - a01 * m0 - a11 * m1 - a21 * m2;
    o[11] = p2 - a02 * m0 - a12 * m1 - a22 * m2;
}

// ---------------- K2: horizontal sliding + solve -> ab12 (A-layout fp16) ----------------
template<int SW>
__global__ __launch_bounds__(256, 3) void k2h(const h16* __restrict__ vs, h16* __restrict__ ab,
                                              int cs0, int lo2, int hi2) {
    constexpr int SWV = SW + 64, SWA = SW + 32;
    const int i = blockIdx.x * 256 + threadIdx.x;
    const int j0 = lo2 + blockIdx.y * SEGH;
    const int vb = -(cs0 - 32);   // vs local col = image col + vb
    float S[21];
#pragma unroll
    for (int c = 0; c < 21; ++c) S[c] = 0.0f;
    {
        int lo = j0 - RAD; if (lo < 0) lo = 0;
        int hi = j0 + RAD; if (hi > WWI - 1) hi = WWI - 1;
        for (int k = lo; k <= hi; ++k) {
            const h16* p = vs + (size_t)(k + vb) * HH + i;
#pragma unroll
            for (int c = 0; c < 21; ++c) S[c] += (float)p[(size_t)c * SWV * HH];
        }
    }
    const float cx = (float)cnt1d(i);
    for (int jj = 0; jj < SEGH; jj += 2) {
        const int j = j0 + jj;
        float o0[12], o1[12];
        solve_ab(S, 1.0f / (cx * (float)cnt1d(j)), o0);
        { // advance j -> j+1 (j+1 < hi2 guaranteed: ranges are even)
            const int ac = j + RAD + 1, sc = j - RAD;
            if (ac < WWI) {
                const h16* p = vs + (size_t)(ac + vb) * HH + i;
#pragma unroll
                for (int c = 0; c < 21; ++c) S[c] += (float)p[(size_t)c * SWV * HH];
            }
            if (sc >= 0) {
                const h16* p = vs + (size_t)(sc + vb) * HH + i;
#pragma unroll
                for (int c = 0; c < 21; ++c) S[c] -= (float)p[(size_t)c * SWV * HH];
            }
        }
        solve_ab(S, 1.0f / (cx * (float)cnt1d(j + 1)), o1);
        const int m0 = j - lo2;
        h16* obase = ab + (size_t)i * SWA + m0;
#pragma unroll
        for (int c = 0; c < 12; ++c)
            st2(obase + (size_t)c * HH * SWA, o0[c], o1[c]);
        if (j + 2 < hi2) { // advance j+1 -> j+2
            const int ac = j + RAD + 2, sc = j + 1 - RAD;
            if (ac < WWI) {
                const h16* p = vs + (size_t)(ac + vb) * HH + i;
#pragma unroll
                for (int c = 0; c < 21; ++c) S[c] += (float)p[(size_t)c * SWV * HH];
            }
            if (sc >= 0) {
                const h16* p = vs + (size_t)(sc + vb) * HH + i;
#pragma unroll
                for (int c = 0; c < 21; ++c) S[c] -= (float)p[(size_t)c * SWV * HH];
            }
        }
    }
}

// ---------------- K3: vertical sliding box-sum of ab -> vs2 (B-layout fp16) ----------------
template<int SW>
__global__ __launch_bounds__(256, 4) void k3v(const h16* __restrict__ ab, h16* __restrict__ vs2,
                                              int mcount) {
    constexpr int SWA = SW + 32;
    const int m = blockIdx.x * 256 + threadIdx.x;
    if (m >= mcount) return;
    const int i0 = blockIdx.y * SEGV;
    float S[12];
#pragma unroll
    for (int c = 0; c < 12; ++c) S[c] = 0.0f;
    {
        int lo = i0 - RAD; if (lo < 0) lo = 0;
        int hi = i0 + RAD; if (hi > HH - 1) hi = HH - 1;
        for (int k = lo; k <= hi; ++k) {
            const h16* p = ab + (size_t)k * SWA + m;
#pragma unroll
            for (int c = 0; c < 12; ++c) S[c] += (float)p[(size_t)c * HH * SWA];
        }
    }
    h16* vb = vs2 + (size_t)m * HH + i0;
    for (int ii = 0; ii < SEGV; ii += 2) {
        const int i = i0 + ii;
        float P[12];
#pragma unroll
        for (int c = 0; c < 12; ++c) P[c] = S[c];
        if (i + RAD + 1 < HH) {
            const h16* p = ab + (size_t)(i + RAD + 1) * SWA + m;
#pragma unroll
            for (int c = 0; c < 12; ++c) S[c] += (float)p[(size_t)c * HH * SWA];
        }
        if (i - RAD >= 0) {
            const h16* p = ab + (size_t)(i - RAD) * SWA + m;
#pragma unroll
            for (int c = 0; c < 12; ++c) S[c] -= (float)p[(size_t)c * HH * SWA];
        }
#pragma unroll
        for (int c = 0; c < 12; ++c)
            st2(vb + (size_t)c * SWA * HH + ii, P[c], S[c]);
        if (i + RAD + 2 < HH) {
            const h16* p = ab + (size_t)(i + RAD + 2) * SWA + m;
#pragma unroll
            for (int c = 0; c < 12; ++c) S[c] += (float)p[(size_t)c * HH * SWA];
        }
        if (i + 1 - RAD >= 0) {
            const h16* p = ab + (size_t)(i + 1 - RAD) * SWA + m;
#pragma unroll
            for (int c = 0; c < 12; ++c) S[c] -= (float)p[(size_t)c * HH * SWA];
        }
    }
}

// ---------------- K4: horizontal sliding + q = mean_a . guide + mean_b ----------------
template<int SW>
__global__ __launch_bounds__(256, 4) void k4h(const h16* __restrict__ vs2, const h16* __restrict__ gT,
                                              float* __restrict__ outp, int cs0, int lo2) {
    constexpr int SWA = SW + 32;
    const int i = blockIdx.x * 256 + threadIdx.x;
    const int j0 = cs0 + blockIdx.y * SEGH;
    float S[12];
#pragma unroll
    for (int c = 0; c < 12; ++c) S[c] = 0.0f;
    {
        int lo = j0 - RAD; if (lo < 0) lo = 0;
        int hi = j0 + RAD; if (hi > WWI - 1) hi = WWI - 1;
        for (int k = lo; k <= hi; ++k) {
            const h16* p = vs2 + (size_t)(k - lo2) * HH + i;
#pragma unroll
            for (int c = 0; c < 12; ++c) S[c] += (float)p[(size_t)c * SWA * HH];
        }
    }
    const float cx = (float)cnt1d(i);
    const int jend = cs0 + SW;
    for (int jj4 = 0; jj4 < SEGH; jj4 += 4) {
        float buf[4][3];
#pragma unroll
        for (int u = 0; u < 4; ++u) {
            const int j = j0 + jj4 + u;
            const float rN = 1.0f / (cx * (float)cnt1d(j));
            const float g0 = (float)gT[((size_t)0 * SW + (j - cs0)) * HH + i];
            const float g1 = (float)gT[((size_t)1 * SW + (j - cs0)) * HH + i];
            const float g2 = (float)gT[((size_t)2 * SW + (j - cs0)) * HH + i];
            buf[u][0] = (S[0] * g0 + S[3] * g1 + S[6] * g2 + S[9])  * rN;
            buf[u][1] = (S[1] * g0 + S[4] * g1 + S[7] * g2 + S[10]) * rN;
            buf[u][2] = (S[2] * g0 + S[5] * g1 + S[8] * g2 + S[11]) * rN;
            if (j + 1 < jend) {
                const int ac = j + RAD + 1, sc = j - RAD;
                if (ac < WWI) {
                    const h16* p = vs2 + (size_t)(ac - lo2) * HH + i;
#pragma unroll
                    for (int c = 0; c < 12; ++c) S[c] += (float)p[(size_t)c * SWA * HH];
                }
                if (sc >= 0) {
                    const h16* p = vs2 + (size_t)(sc - lo2) * HH + i;
#pragma unroll
                    for (int c = 0; c < 12; ++c) S[c] -= (float)p[(size_t)c * SWA * HH];
                }
            }
        }
        float* ob = outp + (size_t)i * WWI + (j0 + jj4);
#pragma unroll
        for (int c = 0; c < 3; ++c)
            *reinterpret_cast<float4*>(ob + (size_t)c * PLN) =
                make_float4(buf[0][c], buf[1][c], buf[2][c], buf[3][c]);
    }
}

// ---------------- host ----------------
template<int SW>
static void run_pipeline(const float* g, const float* s, float* outp, void* d_ws,
                         hipStream_t stream) {
    constexpr int SWV = SW + 64, SWA = SW + 32;
    h16* vs = (h16*)d_ws;
    h16* ab = vs + (size_t)21 * SWV * HH;
    h16* gT = ab + (size_t)12 * HH * SWA;
    h16* vs2 = vs;  // reuse (vs dead after k2h)
    const int nstrips = WWI / SW;
    for (int sidx = 0; sidx < nstrips; ++sidx) {
        const int cs0 = sidx * SW;
        const int lo1 = max(0, cs0 - 32), hi1 = min(WWI, cs0 + SW + 32);
        const int lo2 = max(0, cs0 - 16), hi2 = min(WWI, cs0 + SW + 16);
        dim3 blk(256, 1, 1);
        k0_gt<SW><<<dim3(SW / 64, HH / 64, 1), blk, 0, stream>>>(g, gT, cs0);
        k1v<SW><<<dim3((hi1 - lo1 + 255) / 256, HH / SEGV, 1), blk, 0, stream>>>(g, s, vs, cs0, lo1, hi1);
        k2h<SW><<<dim3(HH / 256, (hi2 - lo2) / SEGH, 1), blk, 0, stream>>>(vs, ab, cs0, lo2, hi2);
        k3v<SW><<<dim3((hi2 - lo2 + 255) / 256, HH / SEGV, 1), blk, 0, stream>>>(ab, vs2, hi2 - lo2);
        k4h<SW><<<dim3(HH / 256, SW / SEGH, 1), blk, 0, stream>>>(vs2, gT, outp, cs0, lo2);
    }
}

static size_t need_bytes(int sw) {
    return ((size_t)21 * (sw + 64) * HH + (size_t)12 * HH * (sw + 32) + (size_t)3 * sw * HH) * sizeof(h16);
}

extern "C" void kernel_launch(void* const* d_in, const int* in_sizes, int n_in,
                              void* d_out, int out_size, void* d_ws, size_t ws_size,
                              hipStream_t stream) {
    const float* g = (const float*)d_in[0];
    const float* s = (const float*)d_in[1];
    float* outp = (float*)d_out;

    fprintf(stderr, "[gf] ws_size=%zu need: 2048->%zu 1024->%zu 512->%zu 256->%zu 128->%zu\n",
            ws_size, need_bytes(2048), need_bytes(1024), need_bytes(512), need_bytes(256), need_bytes(128));

    if (ws_size >= need_bytes(2048))      run_pipeline<2048>(g, s, outp, d_ws, stream);
    else if (ws_size >= need_bytes(1024)) run_pipeline<1024>(g, s, outp, d_ws, stream);
    else if (ws_size >= need_bytes(512))  run_pipeline<512>(g, s, outp, d_ws, stream);
    else if (ws_size >= need_bytes(256))  run_pipeline<256>(g, s, outp, d_ws, stream);
    else                                  run_pipeline<128>(g, s, outp, d_ws, stream);
}

// Round 4
// 364.720 us; speedup vs baseline: 9.0537x; 4.9199x over previous
//
#include <hip/hip_runtime.h>
#include <cstdio>

#define HH 2048
#define WWI 2048
#define RAD 16
#define EPSF 1e-4f
#define BROWS 64

typedef _Float16 h16;
constexpr size_t PLN = (size_t)HH * WWI;

__device__ __forceinline__ int cnt1d(int p, int n) {
    int lo = p - RAD; if (lo < 0) lo = 0;
    int hi = p + RAD; if (hi > n - 1) hi = n - 1;
    return hi - lo + 1;
}

// ---- wave64 inclusive scan via DPP (VALU pipe, no LDS) ----
template<int CTRL, int RM>
__device__ __forceinline__ float dpp_add(float x) {
    int t = __builtin_amdgcn_update_dpp(0, __builtin_bit_cast(int, x), CTRL, RM, 0xf, false);
    return x + __builtin_bit_cast(float, t);
}
__device__ __forceinline__ float wscan(float x) {
    x = dpp_add<0x111, 0xf>(x);   // row_shr:1
    x = dpp_add<0x112, 0xf>(x);   // row_shr:2
    x = dpp_add<0x114, 0xf>(x);   // row_shr:4
    x = dpp_add<0x118, 0xf>(x);   // row_shr:8
    x = dpp_add<0x142, 0xa>(x);   // row_bcast:15 -> rows 1,3
    x = dpp_add<0x143, 0xc>(x);   // row_bcast:31 -> rows 2,3
    return x;
}
__device__ __forceinline__ float bperm(int byteaddr, float v) {
    return __builtin_bit_cast(float,
        __builtin_amdgcn_ds_bpermute(byteaddr, __builtin_bit_cast(int, v)));
}

// ---- accumulate/subtract one row of the 21 product channels ----
template<bool ADD>
__device__ __forceinline__ void acc21(const float* __restrict__ g, const float* __restrict__ s,
                                      int row, int col, bool ok, float S[21]) {
    if (!ok) return;
    const size_t b = (size_t)row * WWI + col;
    const float v0 = g[b], v1 = g[PLN + b], v2 = g[2 * PLN + b];
    const float v3 = s[b], v4 = s[PLN + b], v5 = s[2 * PLN + b];
    float p[21];
    p[0] = v0; p[1] = v1; p[2] = v2; p[3] = v3; p[4] = v4; p[5] = v5;
    p[6] = v0 * v3; p[7] = v0 * v4; p[8] = v0 * v5;
    p[9] = v1 * v3; p[10] = v1 * v4; p[11] = v1 * v5;
    p[12] = v2 * v3; p[13] = v2 * v4; p[14] = v2 * v5;
    p[15] = v0 * v0; p[16] = v0 * v1; p[17] = v0 * v2;
    p[18] = v1 * v1; p[19] = v1 * v2; p[20] = v2 * v2;
#pragma unroll
    for (int c = 0; c < 21; ++c) { if constexpr (ADD) S[c] += p[c]; else S[c] -= p[c]; }
}

template<bool ADD>
__device__ __forceinline__ void acc12(const h16* __restrict__ ab, int row, int col, bool ok,
                                      float S[12]) {
    if (!ok) return;
    const h16* p = ab + (size_t)row * WWI + col;
#pragma unroll
    for (int c = 0; c < 12; ++c) {
        const float v = (float)p[(size_t)c * PLN];
        if constexpr (ADD) S[c] += v; else S[c] -= v;
    }
}

__device__ __forceinline__ void solve_ab(const float S[21], float rN, float o[12]) {
    const float m0 = S[0] * rN, m1 = S[1] * rN, m2 = S[2] * rN;
    const float p0 = S[3] * rN, p1 = S[4] * rN, p2 = S[5] * rN;
    const float c00 = S[6] * rN - m0 * p0;
    const float c01 = S[7] * rN - m0 * p1;
    const float c02 = S[8] * rN - m0 * p2;
    const float c10 = S[9] * rN - m1 * p0;
    const float c11 = S[10] * rN - m1 * p1;
    const float c12 = S[11] * rN - m1 * p2;
    const float c20 = S[12] * rN - m2 * p0;
    const float c21 = S[13] * rN - m2 * p1;
    const float c22 = S[14] * rN - m2 * p2;
    const float vrr = S[15] * rN - m0 * m0 + EPSF;
    const float vrg = S[16] * rN - m0 * m1;
    const float vrb = S[17] * rN - m0 * m2;
    const float vgg = S[18] * rN - m1 * m1 + EPSF;
    const float vgb = S[19] * rN - m1 * m2;
    const float vbb = S[20] * rN - m2 * m2 + EPSF;
    const float det = vrr * vgg * vbb + vrg * vgb * vrb + vrb * vrg * vgb
                    - vrb * vgg * vrb - vrg * vrg * vbb - vrr * vgb * vgb;
    const float id = 1.0f / det;
    const float irr =  (vgg * vbb - vgb * vgb) * id;
    const float irg = -(vrg * vbb - vrb * vgb) * id;
    const float irb =  (vrg * vgb - vrb * vgg) * id;
    const float igg =  (vrr * vbb - vrb * vrb) * id;
    const float igb = -(vrr * vgb - vrb * vrg) * id;
    const float ibb =  (vrr * vgg - vrg * vrg) * id;
    const float a00 = c00 * irr + c10 * irg + c20 * irb;
    const float a01 = c01 * irr + c11 * irg + c21 * irb;
    const float a02 = c02 * irr + c12 * irg + c22 * irb;
    const float a10 = c00 * irg + c10 * igg + c20 * igb;
    const float a11 = c01 * irg + c11 * igg + c21 * igb;
    const float a12 = c02 * irg + c12 * igg + c22 * igb;
    const float a20 = c00 * irb + c10 * igb + c20 * ibb;
    const float a21 = c01 * irb + c11 * igb + c21 * ibb;
    const float a22 = c02 * irb + c12 * igb + c22 * ibb;
    o[0] = a00; o[1] = a01; o[2] = a02;
    o[3] = a10; o[4] = a11; o[5] = a12;
    o[6] = a20; o[7] = a21; o[8] = a22;
    o[9]  = p0 - a00 * m0 - a10 * m1 - a20 * m2;
    o[10] = p1 - a01 * m0 - a11 * m1 - a21 * m2;
    o[11] = p2 - a02 * m0 - a12 * m1 - a22 * m2;
}

// ---- Stage 1: products -> 2D box sums -> solve -> ab (12 fp16 planes) ----
__global__ __launch_bounds__(256) void kA(const float* __restrict__ g,
                                          const float* __restrict__ s,
                                          h16* __restrict__ ab) {
    const int lane = threadIdx.x & 63;
    const int wg   = blockIdx.x * 4 + (threadIdx.x >> 6);
    const int x0   = wg * 32;
    const int col  = x0 - RAD + lane;
    const bool okc = (unsigned)col < (unsigned)WWI;
    const int r0   = blockIdx.y * BROWS;
    const int addrA = ((lane + 16) & 63) * 4;
    const int addrB = (lane >= 17 ? lane - 17 : 0) * 4;
    const bool subok = lane >= 17;
    const bool outl  = (lane >= 16) && (lane < 48);

    float S[21];
#pragma unroll
    for (int c = 0; c < 21; ++c) S[c] = 0.f;
    {
        int lo = r0 - RAD; if (lo < 0) lo = 0;
        int hi = r0 + RAD; if (hi > HH - 1) hi = HH - 1;
        for (int r = lo; r <= hi; ++r) acc21<true>(g, s, r, col, okc, S);
    }
    const float cx = (float)cnt1d(col, WWI);
    for (int ii = 0; ii < BROWS; ++ii) {
        const int i = r0 + ii;
        float H[21];
#pragma unroll
        for (int c = 0; c < 21; ++c) {
            const float sc = wscan(S[c]);
            const float hv = bperm(addrA, sc);
            const float lv = bperm(addrB, sc);
            H[c] = hv - (subok ? lv : 0.f);
        }
        const float rN = 1.0f / (cx * (float)cnt1d(i, HH));
        float o[12];
        solve_ab(H, rN, o);
        if (outl) {
            h16* p = ab + (size_t)i * WWI + col;
#pragma unroll
            for (int c = 0; c < 12; ++c) p[c * PLN] = (h16)o[c];
        }
        const int ra = i + RAD + 1, rs = i - RAD;
        if (ra < HH) acc21<true >(g, s, ra, col, okc, S);
        if (rs >= 0) acc21<false>(g, s, rs, col, okc, S);
    }
}

// ---- Stage 2: 2D box sums of ab -> q = mean_a . guide + mean_b ----
__global__ __launch_bounds__(256) void kB(const h16* __restrict__ ab,
                                          const float* __restrict__ g,
                                          float* __restrict__ outp) {
    const int lane = threadIdx.x & 63;
    const int wg   = blockIdx.x * 4 + (threadIdx.x >> 6);
    const int x0   = wg * 32;
    const int col  = x0 - RAD + lane;
    const bool okc = (unsigned)col < (unsigned)WWI;
    const int r0   = blockIdx.y * BROWS;
    const int addrA = ((lane + 16) & 63) * 4;
    const int addrB = (lane >= 17 ? lane - 17 : 0) * 4;
    const bool subok = lane >= 17;
    const bool outl  = (lane >= 16) && (lane < 48);

    float S[12];
#pragma unroll
    for (int c = 0; c < 12; ++c) S[c] = 0.f;
    {
        int lo = r0 - RAD; if (lo < 0) lo = 0;
        int hi = r0 + RAD; if (hi > HH - 1) hi = HH - 1;
        for (int r = lo; r <= hi; ++r) acc12<true>(ab, r, col, okc, S);
    }
    const float cx = (float)cnt1d(col, WWI);
    for (int ii = 0; ii < BROWS; ++ii) {
        const int i = r0 + ii;
        float H[12];
#pragma unroll
        for (int c = 0; c < 12; ++c) {
            const float sc = wscan(S[c]);
            const float hv = bperm(addrA, sc);
            const float lv = bperm(addrB, sc);
            H[c] = hv - (subok ? lv : 0.f);
        }
        if (outl) {
            const float rN = 1.0f / (cx * (float)cnt1d(i, HH));
            const size_t b = (size_t)i * WWI + col;
            const float g0 = g[b], g1 = g[PLN + b], g2 = g[2 * PLN + b];
            outp[b]           = (H[0] * g0 + H[3] * g1 + H[6] * g2 + H[9])  * rN;
            outp[PLN + b]     = (H[1] * g0 + H[4] * g1 + H[7] * g2 + H[10]) * rN;
            outp[2 * PLN + b] = (H[2] * g0 + H[5] * g1 + H[8] * g2 + H[11]) * rN;
        }
        const int ra = i + RAD + 1, rs = i - RAD;
        if (ra < HH) acc12<true >(ab, ra, col, okc, S);
        if (rs >= 0) acc12<false>(ab, rs, col, okc, S);
    }
}

extern "C" void kernel_launch(void* const* d_in, const int* in_sizes, int n_in,
                              void* d_out, int out_size, void* d_ws, size_t ws_size,
                              hipStream_t stream) {
    const float* g = (const float*)d_in[0];
    const float* s = (const float*)d_in[1];
    float* outp = (float*)d_out;
    h16* ab = (h16*)d_ws;

    const size_t need = 12 * PLN * sizeof(h16);
    if (ws_size < need)
        fprintf(stderr, "[gf] WARNING ws_size=%zu < need=%zu\n", ws_size, need);

    dim3 blk(256, 1, 1);
    dim3 grd(WWI / 32 / 4, HH / BROWS, 1);   // (16, 32)
    kA<<<grd, blk, 0, stream>>>(g, s, ab);
    kB<<<grd, blk, 0, stream>>>(ab, g, outp);
}

// Round 6
// 240.542 us; speedup vs baseline: 13.7276x; 1.5162x over previous
//
#include <hip/hip_runtime.h>
#include <cstdio>
#include <cstdint>

#define HH 2048
#define WWI 2048
#define RAD 16
#define EPSF 1e-4f
#define BRA 16
#define BRB 32

typedef _Float16 h16;
constexpr size_t PLN = (size_t)HH * WWI;
constexpr int ROWB = WWI * 4;          // row stride in bytes (fp32 / u32 planes)

__device__ __forceinline__ int cnt1d(int p, int n) {
    int lo = p - RAD; if (lo < 0) lo = 0;
    int hi = p + RAD; if (hi > n - 1) hi = n - 1;
    return hi - lo + 1;
}

__device__ __forceinline__ float ldf(const float* __restrict__ p, int boff) {
    return *reinterpret_cast<const float*>(reinterpret_cast<const char*>(p) + boff);
}
__device__ __forceinline__ uint32_t ldu(const uint32_t* __restrict__ p, int boff) {
    return *reinterpret_cast<const uint32_t*>(reinterpret_cast<const char*>(p) + boff);
}
__device__ __forceinline__ void stu(uint32_t* __restrict__ p, int boff, uint32_t v) {
    *reinterpret_cast<uint32_t*>(reinterpret_cast<char*>(p) + boff) = v;
}
__device__ __forceinline__ void stf(float* __restrict__ p, int boff, float v) {
    *reinterpret_cast<float*>(reinterpret_cast<char*>(p) + boff) = v;
}
__device__ __forceinline__ uint32_t pk(float a, float b) {
    union { h16 h[2]; uint32_t u; } t;
    t.h[0] = (h16)a; t.h[1] = (h16)b; return t.u;
}
__device__ __forceinline__ float2 upk(uint32_t u) {
    union { uint32_t u; h16 h[2]; } t; t.u = u;
    return make_float2((float)t.h[0], (float)t.h[1]);
}

// ---- wave64 inclusive scan via DPP ----
template<int CTRL, int RM>
__device__ __forceinline__ float dpp_add(float x) {
    int t = __builtin_amdgcn_update_dpp(0, __builtin_bit_cast(int, x), CTRL, RM, 0xf, false);
    return x + __builtin_bit_cast(float, t);
}
__device__ __forceinline__ float wscan(float x) {
    x = dpp_add<0x111, 0xf>(x);
    x = dpp_add<0x112, 0xf>(x);
    x = dpp_add<0x114, 0xf>(x);
    x = dpp_add<0x118, 0xf>(x);
    x = dpp_add<0x142, 0xa>(x);
    x = dpp_add<0x143, 0xc>(x);
    return x;
}
// NOTE: must be called with FULL exec (all 64 lanes) — ds_bpermute reads from
// inactive lanes return undefined data (this caused Round-5's NaN).
__device__ __forceinline__ float bperm(int byteaddr, float v) {
    return __builtin_bit_cast(float,
        __builtin_amdgcn_ds_bpermute(byteaddr, __builtin_bit_cast(int, v)));
}

template<bool ADD>
__device__ __forceinline__ void acc21(const float* __restrict__ g0, const float* __restrict__ g1,
                                      const float* __restrict__ g2, const float* __restrict__ s0,
                                      const float* __restrict__ s1, const float* __restrict__ s2,
                                      int boff, bool ok, float S[21]) {
    if (!ok) return;
    const float v0 = ldf(g0, boff), v1 = ldf(g1, boff), v2 = ldf(g2, boff);
    const float v3 = ldf(s0, boff), v4 = ldf(s1, boff), v5 = ldf(s2, boff);
    float p[21];
    p[0] = v0; p[1] = v1; p[2] = v2; p[3] = v3; p[4] = v4; p[5] = v5;
    p[6] = v0 * v3; p[7] = v0 * v4; p[8] = v0 * v5;
    p[9] = v1 * v3; p[10] = v1 * v4; p[11] = v1 * v5;
    p[12] = v2 * v3; p[13] = v2 * v4; p[14] = v2 * v5;
    p[15] = v0 * v0; p[16] = v0 * v1; p[17] = v0 * v2;
    p[18] = v1 * v1; p[19] = v1 * v2; p[20] = v2 * v2;
#pragma unroll
    for (int c = 0; c < 21; ++c) { if constexpr (ADD) S[c] += p[c]; else S[c] -= p[c]; }
}

template<bool ADD>
__device__ __forceinline__ void acc12(const uint32_t* __restrict__ a0, const uint32_t* __restrict__ a1,
                                      const uint32_t* __restrict__ a2, const uint32_t* __restrict__ a3,
                                      const uint32_t* __restrict__ a4, const uint32_t* __restrict__ a5,
                                      int boff, bool ok, float S[12]) {
    if (!ok) return;
    const uint32_t u0 = ldu(a0, boff), u1 = ldu(a1, boff), u2 = ldu(a2, boff);
    const uint32_t u3 = ldu(a3, boff), u4 = ldu(a4, boff), u5 = ldu(a5, boff);
    const float2 f0 = upk(u0), f1 = upk(u1), f2 = upk(u2);
    const float2 f3 = upk(u3), f4 = upk(u4), f5 = upk(u5);
    if constexpr (ADD) {
        S[0] += f0.x; S[1] += f0.y; S[2] += f1.x; S[3] += f1.y;
        S[4] += f2.x; S[5] += f2.y; S[6] += f3.x; S[7] += f3.y;
        S[8] += f4.x; S[9] += f4.y; S[10] += f5.x; S[11] += f5.y;
    } else {
        S[0] -= f0.x; S[1] -= f0.y; S[2] -= f1.x; S[3] -= f1.y;
        S[4] -= f2.x; S[5] -= f2.y; S[6] -= f3.x; S[7] -= f3.y;
        S[8] -= f4.x; S[9] -= f4.y; S[10] -= f5.x; S[11] -= f5.y;
    }
}

__device__ __forceinline__ void solve_ab(const float S[21], float rN, float o[12]) {
    const float m0 = S[0] * rN, m1 = S[1] * rN, m2 = S[2] * rN;
    const float p0 = S[3] * rN, p1 = S[4] * rN, p2 = S[5] * rN;
    const float c00 = S[6] * rN - m0 * p0;
    const float c01 = S[7] * rN - m0 * p1;
    const float c02 = S[8] * rN - m0 * p2;
    const float c10 = S[9] * rN - m1 * p0;
    const float c11 = S[10] * rN - m1 * p1;
    const float c12 = S[11] * rN - m1 * p2;
    const float c20 = S[12] * rN - m2 * p0;
    const float c21 = S[13] * rN - m2 * p1;
    const float c22 = S[14] * rN - m2 * p2;
    const float vrr = S[15] * rN - m0 * m0 + EPSF;
    const float vrg = S[16] * rN - m0 * m1;
    const float vrb = S[17] * rN - m0 * m2;
    const float vgg = S[18] * rN - m1 * m1 + EPSF;
    const float vgb = S[19] * rN - m1 * m2;
    const float vbb = S[20] * rN - m2 * m2 + EPSF;
    const float det = vrr * vgg * vbb + vrg * vgb * vrb + vrb * vrg * vgb
                    - vrb * vgg * vrb - vrg * vrg * vbb - vrr * vgb * vgb;
    const float id = __builtin_amdgcn_rcpf(det);
    const float irr =  (vgg * vbb - vgb * vgb) * id;
    const float irg = -(vrg * vbb - vrb * vgb) * id;
    const float irb =  (vrg * vgb - vrb * vgg) * id;
    const float igg =  (vrr * vbb - vrb * vrb) * id;
    const float igb = -(vrr * vgb - vrb * vrg) * id;
    const float ibb =  (vrr * vgg - vrg * vrg) * id;
    const float a00 = c00 * irr + c10 * irg + c20 * irb;
    const float a01 = c01 * irr + c11 * irg + c21 * irb;
    const float a02 = c02 * irr + c12 * irg + c22 * irb;
    const float a10 = c00 * irg + c10 * igg + c20 * igb;
    const float a11 = c01 * irg + c11 * igg + c21 * igb;
    const float a12 = c02 * irg + c12 * igg + c22 * igb;
    const float a20 = c00 * irb + c10 * igb + c20 * ibb;
    const float a21 = c01 * irb + c11 * igb + c21 * ibb;
    const float a22 = c02 * irb + c12 * igb + c22 * ibb;
    o[0] = a00; o[1] = a01; o[2] = a02;
    o[3] = a10; o[4] = a11; o[5] = a12;
    o[6] = a20; o[7] = a21; o[8] = a22;
    o[9]  = p0 - a00 * m0 - a10 * m1 - a20 * m2;
    o[10] = p1 - a01 * m0 - a11 * m1 - a21 * m2;
    o[11] = p2 - a02 * m0 - a12 * m1 - a22 * m2;
}

// ---- Stage 1 ----
__global__ __launch_bounds__(256) void kA(const float* __restrict__ g,
                                          const float* __restrict__ s,
                                          uint32_t* __restrict__ ab) {
    const int lane = threadIdx.x & 63;
    const int wv   = blockIdx.x * 4 + (threadIdx.x >> 6);
    const int x0   = wv * 32;
    const int col  = x0 - RAD + lane;
    const bool okc = (unsigned)col < (unsigned)WWI;
    const int r0   = blockIdx.y * BRA;
    const int addrA = ((lane + 16) & 63) * 4;
    const int addrB = (lane >= 17 ? lane - 17 : 0) * 4;
    const bool subok = lane >= 17;
    const bool outl  = (lane >= 16) && (lane < 48);

    const float* g0 = g;            const float* g1 = g + PLN;  const float* g2 = g + 2 * PLN;
    const float* s0 = s;            const float* s1 = s + PLN;  const float* s2 = s + 2 * PLN;
    uint32_t* a0 = ab;              uint32_t* a1 = ab + PLN;    uint32_t* a2 = ab + 2 * PLN;
    uint32_t* a3 = ab + 3 * PLN;    uint32_t* a4 = ab + 4 * PLN; uint32_t* a5 = ab + 5 * PLN;

    float S[21];
#pragma unroll
    for (int c = 0; c < 21; ++c) S[c] = 0.f;
    {
        int lo = r0 - RAD; if (lo < 0) lo = 0;
        int hi = r0 + RAD; if (hi > HH - 1) hi = HH - 1;
        int boff = lo * ROWB + col * 4;
        for (int r = lo; r <= hi; ++r) {
            acc21<true>(g0, g1, g2, s0, s1, s2, boff, okc, S);
            boff += ROWB;
        }
    }
    const float cx = (float)cnt1d(col, WWI);
    int raOff = (r0 + RAD + 1) * ROWB + col * 4;
    int rsOff = (r0 - RAD) * ROWB + col * 4;
    int oOff  = r0 * ROWB + col * 4;
    for (int ii = 0; ii < BRA; ++ii) {
        const int i = r0 + ii;
        float H[21];
#pragma unroll
        for (int c = 0; c < 21; ++c) {
            const float sc = wscan(S[c]);
            const float hv = bperm(addrA, sc);   // full-exec
            const float lv = bperm(addrB, sc);   // full-exec
            H[c] = hv - (subok ? lv : 0.f);
        }
        const float rN = __builtin_amdgcn_rcpf(cx * (float)cnt1d(i, HH));
        float o[12];
        solve_ab(H, rN, o);
        if (outl) {
            stu(a0, oOff, pk(o[0], o[1]));
            stu(a1, oOff, pk(o[2], o[3]));
            stu(a2, oOff, pk(o[4], o[5]));
            stu(a3, oOff, pk(o[6], o[7]));
            stu(a4, oOff, pk(o[8], o[9]));
            stu(a5, oOff, pk(o[10], o[11]));
        }
        if (i + RAD + 1 < HH) acc21<true >(g0, g1, g2, s0, s1, s2, raOff, okc, S);
        if (i - RAD >= 0)     acc21<false>(g0, g1, g2, s0, s1, s2, rsOff, okc, S);
        raOff += ROWB; rsOff += ROWB; oOff += ROWB;
    }
}

// ---- Stage 2 ----
__global__ __launch_bounds__(256) void kB(const uint32_t* __restrict__ ab,
                                          const float* __restrict__ g,
                                          float* __restrict__ outp) {
    const int lane = threadIdx.x & 63;
    const int wv   = blockIdx.x * 4 + (threadIdx.x >> 6);
    const int x0   = wv * 32;
    const int col  = x0 - RAD + lane;
    const bool okc = (unsigned)col < (unsigned)WWI;
    const int r0   = blockIdx.y * BRB;
    const int addrA = ((lane + 16) & 63) * 4;
    const int addrB = (lane >= 17 ? lane - 17 : 0) * 4;
    const bool subok = lane >= 17;
    const bool outl  = (lane >= 16) && (lane < 48);

    const uint32_t* a0 = ab;           const uint32_t* a1 = ab + PLN;    const uint32_t* a2 = ab + 2 * PLN;
    const uint32_t* a3 = ab + 3 * PLN; const uint32_t* a4 = ab + 4 * PLN; const uint32_t* a5 = ab + 5 * PLN;
    const float* g0 = g;  const float* g1 = g + PLN;  const float* g2 = g + 2 * PLN;
    float* o0 = outp;     float* o1 = outp + PLN;     float* o2 = outp + 2 * PLN;

    float S[12];
#pragma unroll
    for (int c = 0; c < 12; ++c) S[c] = 0.f;
    {
        int lo = r0 - RAD; if (lo < 0) lo = 0;
        int hi = r0 + RAD; if (hi > HH - 1) hi = HH - 1;
        int boff = lo * ROWB + col * 4;
        for (int r = lo; r <= hi; ++r) {
            acc12<true>(a0, a1, a2, a3, a4, a5, boff, okc, S);
            boff += ROWB;
        }
    }
    const float cx = (float)cnt1d(col, WWI);
    int raOff = (r0 + RAD + 1) * ROWB + col * 4;
    int rsOff = (r0 - RAD) * ROWB + col * 4;
    int oOff  = r0 * ROWB + col * 4;
    for (int ii = 0; ii < BRB; ++ii) {
        const int i = r0 + ii;
        float H[12];
#pragma unroll
        for (int c = 0; c < 12; ++c) {
            const float sc = wscan(S[c]);
            const float hv = bperm(addrA, sc);   // full-exec
            const float lv = bperm(addrB, sc);   // full-exec
            H[c] = hv - (subok ? lv : 0.f);
        }
        if (outl) {
            const float rN = __builtin_amdgcn_rcpf(cx * (float)cnt1d(i, HH));
            const float gg0 = ldf(g0, oOff), gg1 = ldf(g1, oOff), gg2 = ldf(g2, oOff);
            stf(o0, oOff, (H[0] * gg0 + H[3] * gg1 + H[6] * gg2 + H[9])  * rN);
            stf(o1, oOff, (H[1] * gg0 + H[4] * gg1 + H[7] * gg2 + H[10]) * rN);
            stf(o2, oOff, (H[2] * gg0 + H[5] * gg1 + H[8] * gg2 + H[11]) * rN);
        }
        if (i + RAD + 1 < HH) acc12<true >(a0, a1, a2, a3, a4, a5, raOff, okc, S);
        if (i - RAD >= 0)     acc12<false>(a0, a1, a2, a3, a4, a5, rsOff, okc, S);
        raOff += ROWB; rsOff += ROWB; oOff += ROWB;
    }
}

extern "C" void kernel_launch(void* const* d_in, const int* in_sizes, int n_in,
                              void* d_out, int out_size, void* d_ws, size_t ws_size,
                              hipStream_t stream) {
    const float* g = (const float*)d_in[0];
    const float* s = (const float*)d_in[1];
    float* outp = (float*)d_out;
    uint32_t* ab = (uint32_t*)d_ws;

    const size_t need = 6 * PLN * sizeof(uint32_t);   // 100.7 MB
    if (ws_size < need)
        fprintf(stderr, "[gf] WARNING ws_size=%zu < need=%zu\n", ws_size, need);

    dim3 blk(256, 1, 1);
    kA<<<dim3(WWI / 128, HH / BRA, 1), blk, 0, stream>>>(g, s, ab);
    kB<<<dim3(WWI / 128, HH / BRB, 1), blk, 0, stream>>>(ab, g, outp);
}

// Round 7
// 199.816 us; speedup vs baseline: 16.5256x; 1.2038x over previous
//
#include <hip/hip_runtime.h>
#include <cstdio>
#include <cstdint>

#define HH 2048
#define WWI 2048
#define RAD 16
#define EPSF 1e-4f
#define BRA 16
#define BRB 32
#define W_OUT 94      // output cols per wave (pairs scheme: 128 loaded, 94 produced)

typedef _Float16 h16;
constexpr size_t PLN = (size_t)HH * WWI;
constexpr int ROWB = WWI * 4;          // row stride in bytes (fp32 / u32 planes)

__device__ __forceinline__ int cnt1d(int p, int n) {
    int lo = p - RAD; if (lo < 0) lo = 0;
    int hi = p + RAD; if (hi > n - 1) hi = n - 1;
    return hi - lo + 1;
}

__device__ __forceinline__ float ldf(const float* __restrict__ p, int boff) {
    return *reinterpret_cast<const float*>(reinterpret_cast<const char*>(p) + boff);
}
__device__ __forceinline__ float2 ldf2(const float* __restrict__ p, int boff) {
    return *reinterpret_cast<const float2*>(reinterpret_cast<const char*>(p) + boff);
}
__device__ __forceinline__ uint32_t ldu(const uint32_t* __restrict__ p, int boff) {
    return *reinterpret_cast<const uint32_t*>(reinterpret_cast<const char*>(p) + boff);
}
__device__ __forceinline__ void stu2(uint32_t* __restrict__ p, int boff, uint2 v) {
    *reinterpret_cast<uint2*>(reinterpret_cast<char*>(p) + boff) = v;
}
__device__ __forceinline__ void stf(float* __restrict__ p, int boff, float v) {
    *reinterpret_cast<float*>(reinterpret_cast<char*>(p) + boff) = v;
}
__device__ __forceinline__ uint32_t pk(float a, float b) {
    union { h16 h[2]; uint32_t u; } t;
    t.h[0] = (h16)a; t.h[1] = (h16)b; return t.u;
}
__device__ __forceinline__ float2 upk(uint32_t u) {
    union { uint32_t u; h16 h[2]; } t; t.u = u;
    return make_float2((float)t.h[0], (float)t.h[1]);
}

// ---- wave64 inclusive scan via DPP (proven R6) ----
template<int CTRL, int RM>
__device__ __forceinline__ float dpp_add(float x) {
    int t = __builtin_amdgcn_update_dpp(0, __builtin_bit_cast(int, x), CTRL, RM, 0xf, false);
    return x + __builtin_bit_cast(float, t);
}
__device__ __forceinline__ float wscan(float x) {
    x = dpp_add<0x111, 0xf>(x);
    x = dpp_add<0x112, 0xf>(x);
    x = dpp_add<0x114, 0xf>(x);
    x = dpp_add<0x118, 0xf>(x);
    x = dpp_add<0x142, 0xa>(x);
    x = dpp_add<0x143, 0xc>(x);
    return x;
}
// NOTE: must be called with FULL exec — ds_bpermute reads from inactive lanes
// are undefined (Round-5 NaN lesson).
__device__ __forceinline__ float bperm(int byteaddr, float v) {
    return __builtin_bit_cast(float,
        __builtin_amdgcn_ds_bpermute(byteaddr, __builtin_bit_cast(int, v)));
}

template<bool ADD>
__device__ __forceinline__ void prod21(float v0, float v1, float v2,
                                       float v3, float v4, float v5, float S[21]) {
    float p[21];
    p[0] = v0; p[1] = v1; p[2] = v2; p[3] = v3; p[4] = v4; p[5] = v5;
    p[6] = v0 * v3; p[7] = v0 * v4; p[8] = v0 * v5;
    p[9] = v1 * v3; p[10] = v1 * v4; p[11] = v1 * v5;
    p[12] = v2 * v3; p[13] = v2 * v4; p[14] = v2 * v5;
    p[15] = v0 * v0; p[16] = v0 * v1; p[17] = v0 * v2;
    p[18] = v1 * v1; p[19] = v1 * v2; p[20] = v2 * v2;
#pragma unroll
    for (int c = 0; c < 21; ++c) { if constexpr (ADD) S[c] += p[c]; else S[c] -= p[c]; }
}

template<bool ADD>
__device__ __forceinline__ void acc21p(const float* __restrict__ g0, const float* __restrict__ g1,
                                       const float* __restrict__ g2, const float* __restrict__ s0,
                                       const float* __restrict__ s1, const float* __restrict__ s2,
                                       int boff, bool ok, float S0[21], float S1[21]) {
    if (!ok) return;
    const float2 a0 = ldf2(g0, boff), a1 = ldf2(g1, boff), a2 = ldf2(g2, boff);
    const float2 b0 = ldf2(s0, boff), b1 = ldf2(s1, boff), b2 = ldf2(s2, boff);
    prod21<ADD>(a0.x, a1.x, a2.x, b0.x, b1.x, b2.x, S0);
    prod21<ADD>(a0.y, a1.y, a2.y, b0.y, b1.y, b2.y, S1);
}

template<bool ADD>
__device__ __forceinline__ void acc12(const uint32_t* __restrict__ a0, const uint32_t* __restrict__ a1,
                                      const uint32_t* __restrict__ a2, const uint32_t* __restrict__ a3,
                                      const uint32_t* __restrict__ a4, const uint32_t* __restrict__ a5,
                                      int boff, bool ok, float S[12]) {
    if (!ok) return;
    const uint32_t u0 = ldu(a0, boff), u1 = ldu(a1, boff), u2 = ldu(a2, boff);
    const uint32_t u3 = ldu(a3, boff), u4 = ldu(a4, boff), u5 = ldu(a5, boff);
    const float2 f0 = upk(u0), f1 = upk(u1), f2 = upk(u2);
    const float2 f3 = upk(u3), f4 = upk(u4), f5 = upk(u5);
    if constexpr (ADD) {
        S[0] += f0.x; S[1] += f0.y; S[2] += f1.x; S[3] += f1.y;
        S[4] += f2.x; S[5] += f2.y; S[6] += f3.x; S[7] += f3.y;
        S[8] += f4.x; S[9] += f4.y; S[10] += f5.x; S[11] += f5.y;
    } else {
        S[0] -= f0.x; S[1] -= f0.y; S[2] -= f1.x; S[3] -= f1.y;
        S[4] -= f2.x; S[5] -= f2.y; S[6] -= f3.x; S[7] -= f3.y;
        S[8] -= f4.x; S[9] -= f4.y; S[10] -= f5.x; S[11] -= f5.y;
    }
}

__device__ __forceinline__ void solve_ab(const float S[21], float rN, float o[12]) {
    const float m0 = S[0] * rN, m1 = S[1] * rN, m2 = S[2] * rN;
    const float p0 = S[3] * rN, p1 = S[4] * rN, p2 = S[5] * rN;
    const float c00 = S[6] * rN - m0 * p0;
    const float c01 = S[7] * rN - m0 * p1;
    const float c02 = S[8] * rN - m0 * p2;
    const float c10 = S[9] * rN - m1 * p0;
    const float c11 = S[10] * rN - m1 * p1;
    const float c12 = S[11] * rN - m1 * p2;
    const float c20 = S[12] * rN - m2 * p0;
    const float c21 = S[13] * rN - m2 * p1;
    const float c22 = S[14] * rN - m2 * p2;
    const float vrr = S[15] * rN - m0 * m0 + EPSF;
    const float vrg = S[16] * rN - m0 * m1;
    const float vrb = S[17] * rN - m0 * m2;
    const float vgg = S[18] * rN - m1 * m1 + EPSF;
    const float vgb = S[19] * rN - m1 * m2;
    const float vbb = S[20] * rN - m2 * m2 + EPSF;
    const float det = vrr * vgg * vbb + vrg * vgb * vrb + vrb * vrg * vgb
                    - vrb * vgg * vrb - vrg * vrg * vbb - vrr * vgb * vgb;
    const float id = __builtin_amdgcn_rcpf(det);
    const float irr =  (vgg * vbb - vgb * vgb) * id;
    const float irg = -(vrg * vbb - vrb * vgb) * id;
    const float irb =  (vrg * vgb - vrb * vgg) * id;
    const float igg =  (vrr * vbb - vrb * vrb) * id;
    const float igb = -(vrr * vgb - vrb * vrg) * id;
    const float ibb =  (vrr * vgg - vrg * vrg) * id;
    const float a00 = c00 * irr + c10 * irg + c20 * irb;
    const float a01 = c01 * irr + c11 * irg + c21 * irb;
    const float a02 = c02 * irr + c12 * irg + c22 * irb;
    const float a10 = c00 * irg + c10 * igg + c20 * igb;
    const float a11 = c01 * irg + c11 * igg + c21 * igb;
    const float a12 = c02 * irg + c12 * igg + c22 * igb;
    const float a20 = c00 * irb + c10 * igb + c20 * ibb;
    const float a21 = c01 * irb + c11 * igb + c21 * ibb;
    const float a22 = c02 * irb + c12 * igb + c22 * ibb;
    o[0] = a00; o[1] = a01; o[2] = a02;
    o[3] = a10; o[4] = a11; o[5] = a12;
    o[6] = a20; o[7] = a21; o[8] = a22;
    o[9]  = p0 - a00 * m0 - a10 * m1 - a20 * m2;
    o[10] = p1 - a01 * m0 - a11 * m1 - a21 * m2;
    o[11] = p2 - a02 * m0 - a12 * m1 - a22 * m2;
}

// ---- Stage 1: pairs scheme — 2 cols/lane, 94 output cols per wave ----
__global__ __launch_bounds__(128, 3) void kA(const float* __restrict__ g,
                                             const float* __restrict__ s,
                                             uint32_t* __restrict__ ab) {
    const int lane = threadIdx.x & 63;
    const int wv   = blockIdx.x * 2 + (threadIdx.x >> 6);   // 0..21
    const int W0   = wv * W_OUT;
    const int X0   = W0 - 18;                               // even; loads cover [X0, X0+127]
    const int col0 = X0 + 2 * lane;
    const bool okc = (unsigned)col0 < (unsigned)WWI;        // pair-aligned (col0 even)
    const int r0   = blockIdx.y * BRA;
    const int aP17 = ((lane + 17) & 63) * 4;
    const int aP1  = ((lane + 1) & 63) * 4;
    const int j0   = W0 + 2 * lane;                         // = col0 + 18
    const bool outl = (lane <= 46) && (j0 < WWI);

    const float* g0 = g;         const float* g1 = g + PLN;   const float* g2 = g + 2 * PLN;
    const float* s0 = s;         const float* s1 = s + PLN;   const float* s2 = s + 2 * PLN;
    uint32_t* a0 = ab;           uint32_t* a1 = ab + PLN;     uint32_t* a2 = ab + 2 * PLN;
    uint32_t* a3 = ab + 3 * PLN; uint32_t* a4 = ab + 4 * PLN; uint32_t* a5 = ab + 5 * PLN;

    float S0[21], S1[21];
#pragma unroll
    for (int c = 0; c < 21; ++c) { S0[c] = 0.f; S1[c] = 0.f; }
    {
        int lo = r0 - RAD; if (lo < 0) lo = 0;
        int hi = r0 + RAD; if (hi > HH - 1) hi = HH - 1;
        int boff = lo * ROWB + col0 * 4;
        for (int r = lo; r <= hi; ++r) {
            acc21p<true>(g0, g1, g2, s0, s1, s2, boff, okc, S0, S1);
            boff += ROWB;
        }
    }
    const float cx0 = (float)cnt1d(j0, WWI);
    const float cx1 = (float)cnt1d(j0 + 1, WWI);
    int raOff = (r0 + RAD + 1) * ROWB + col0 * 4;
    int rsOff = (r0 - RAD) * ROWB + col0 * 4;
    int oOff  = r0 * ROWB + j0 * 4;
    for (int ii = 0; ii < BRA; ++ii) {
        const int i = r0 + ii;
        float H0[21], H1[21];
#pragma unroll
        for (int c = 0; c < 21; ++c) {
            const float PP  = wscan(S0[c] + S1[c]);   // pair-prefix, full exec
            const float ppa = bperm(aP17, PP);        // PP[L+17]
            const float s1b = bperm(aP17, S1[c]);     // S1[L+17]
            const float s0b = bperm(aP1,  S0[c]);     // S0[L+1]
            const float D = ppa - PP;                 // PP[L+17] - PP[L]
            H0[c] = D - s1b;                          // box for col j0
            H1[c] = D - s0b;                          // box for col j0+1
        }
        const float cy = (float)cnt1d(i, HH);
        float o0[12], o1[12];
        solve_ab(H0, __builtin_amdgcn_rcpf(cx0 * cy), o0);
        solve_ab(H1, __builtin_amdgcn_rcpf(cx1 * cy), o1);
        if (outl) {
            stu2(a0, oOff, make_uint2(pk(o0[0],  o0[1]),  pk(o1[0],  o1[1])));
            stu2(a1, oOff, make_uint2(pk(o0[2],  o0[3]),  pk(o1[2],  o1[3])));
            stu2(a2, oOff, make_uint2(pk(o0[4],  o0[5]),  pk(o1[4],  o1[5])));
            stu2(a3, oOff, make_uint2(pk(o0[6],  o0[7]),  pk(o1[6],  o1[7])));
            stu2(a4, oOff, make_uint2(pk(o0[8],  o0[9]),  pk(o1[8],  o1[9])));
            stu2(a5, oOff, make_uint2(pk(o0[10], o0[11]), pk(o1[10], o1[11])));
        }
        if (i + RAD + 1 < HH) acc21p<true >(g0, g1, g2, s0, s1, s2, raOff, okc, S0, S1);
        if (i - RAD >= 0)     acc21p<false>(g0, g1, g2, s0, s1, s2, rsOff, okc, S0, S1);
        raOff += ROWB; rsOff += ROWB; oOff += ROWB;
    }
}

// ---- Stage 2: unchanged from Round 6 (proven) ----
__global__ __launch_bounds__(256) void kB(const uint32_t* __restrict__ ab,
                                          const float* __restrict__ g,
                                          float* __restrict__ outp) {
    const int lane = threadIdx.x & 63;
    const int wv   = blockIdx.x * 4 + (threadIdx.x >> 6);
    const int x0   = wv * 32;
    const int col  = x0 - RAD + lane;
    const bool okc = (unsigned)col < (unsigned)WWI;
    const int r0   = blockIdx.y * BRB;
    const int addrA = ((lane + 16) & 63) * 4;
    const int addrB = (lane >= 17 ? lane - 17 : 0) * 4;
    const bool subok = lane >= 17;
    const bool outl  = (lane >= 16) && (lane < 48);

    const uint32_t* a0 = ab;           const uint32_t* a1 = ab + PLN;     const uint32_t* a2 = ab + 2 * PLN;
    const uint32_t* a3 = ab + 3 * PLN; const uint32_t* a4 = ab + 4 * PLN; const uint32_t* a5 = ab + 5 * PLN;
    const float* g0 = g;  const float* g1 = g + PLN;  const float* g2 = g + 2 * PLN;
    float* o0 = outp;     float* o1 = outp + PLN;     float* o2 = outp + 2 * PLN;

    float S[12];
#pragma unroll
    for (int c = 0; c < 12; ++c) S[c] = 0.f;
    {
        int lo = r0 - RAD; if (lo < 0) lo = 0;
        int hi = r0 + RAD; if (hi > HH - 1) hi = HH - 1;
        int boff = lo * ROWB + col * 4;
        for (int r = lo; r <= hi; ++r) {
            acc12<true>(a0, a1, a2, a3, a4, a5, boff, okc, S);
            boff += ROWB;
        }
    }
    const float cx = (float)cnt1d(col, WWI);
    int raOff = (r0 + RAD + 1) * ROWB + col * 4;
    int rsOff = (r0 - RAD) * ROWB + col * 4;
    int oOff  = r0 * ROWB + col * 4;
    for (int ii = 0; ii < BRB; ++ii) {
        const int i = r0 + ii;
        float H[12];
#pragma unroll
        for (int c = 0; c < 12; ++c) {
            const float sc = wscan(S[c]);
            const float hv = bperm(addrA, sc);   // full-exec
            const float lv = bperm(addrB, sc);   // full-exec
            H[c] = hv - (subok ? lv : 0.f);
        }
        if (outl) {
            const float rN = __builtin_amdgcn_rcpf(cx * (float)cnt1d(i, HH));
            const float gg0 = ldf(g0, oOff), gg1 = ldf(g1, oOff), gg2 = ldf(g2, oOff);
            stf(o0, oOff, (H[0] * gg0 + H[3] * gg1 + H[6] * gg2 + H[9])  * rN);
            stf(o1, oOff, (H[1] * gg0 + H[4] * gg1 + H[7] * gg2 + H[10]) * rN);
            stf(o2, oOff, (H[2] * gg0 + H[5] * gg1 + H[8] * gg2 + H[11]) * rN);
        }
        if (i + RAD + 1 < HH) acc12<true >(a0, a1, a2, a3, a4, a5, raOff, okc, S);
        if (i - RAD >= 0)     acc12<false>(a0, a1, a2, a3, a4, a5, rsOff, okc, S);
        raOff += ROWB; rsOff += ROWB; oOff += ROWB;
    }
}

extern "C" void kernel_launch(void* const* d_in, const int* in_sizes, int n_in,
                              void* d_out, int out_size, void* d_ws, size_t ws_size,
                              hipStream_t stream) {
    const float* g = (const float*)d_in[0];
    const float* s = (const float*)d_in[1];
    float* outp = (float*)d_out;
    uint32_t* ab = (uint32_t*)d_ws;

    const size_t need = 6 * PLN * sizeof(uint32_t);   // 100.7 MB
    if (ws_size < need)
        fprintf(stderr, "[gf] WARNING ws_size=%zu < need=%zu\n", ws_size, need);

    kA<<<dim3(11, HH / BRA, 1), dim3(128, 1, 1), 0, stream>>>(g, s, ab);
    kB<<<dim3(WWI / 128, HH / BRB, 1), dim3(256, 1, 1), 0, stream>>>(ab, g, outp);
}